// Round 11
// baseline (231.408 us; speedup 1.0000x reference)
//
#include <hip/hip_runtime.h>

// NGCF-style GNN: 3 layers of {sparse sym-normalized aggregation, two 64x64 GEMMs,
// leaky-relu, l2norm}. CSR built on-device per call via bucketed counting sort.
// Single state buffer g[c] = dinv[c]*h[c] (bf16); aggregation is
// ha[r] = dinv[r] * sum g[col]; gemm reconstructs h = g/dinv on the fly.
// Aggregation: TWO nodes per wave, 8 lanes per row (uint4 = 8 bf16/lane),
// 8 edges per load -- measured at the ~6.3 TB/s line-BW ceiling (r10 ledger:
// 1.6M x 128B line touches/layer; fp8 doesn't reduce line traffic, r9).
// GEMMs via mfma_f32_16x16x32_bf16, W pre-packed. copyx folded into csr_k.
// No hipMemsetAsync in graph (captured fill node costs ~58us for 2KB).
//
// Assumes N <= 131072 (512 buckets of 256 rows).

#define LEAKY 0.2f
#define NBK_MAX 512
#define TILE_A 8192
#define BCAP 5120

typedef unsigned short ushort_t;
typedef short short8 __attribute__((ext_vector_type(8)));
typedef float f32x4 __attribute__((ext_vector_type(4)));

__device__ __forceinline__ float lrelu(float z) { return z > 0.f ? z : LEAKY * z; }

__device__ __forceinline__ unsigned f2bf(float f) {  // RNE
  unsigned u = __float_as_uint(f);
  return (u + 0x7FFFu + ((u >> 16) & 1u)) >> 16;
}

__device__ __forceinline__ float bf2f(unsigned u) {
  return __uint_as_float(u << 16);
}

__device__ __forceinline__ int rfl(const int* p) {
  return __builtin_amdgcn_readfirstlane(*p);
}

// ---------- zero tails (replaces in-graph hipMemsetAsync) ----------
__global__ __launch_bounds__(256) void zerotails_k(int* __restrict__ tails, int nbk) {
  int t = blockIdx.x * 256 + threadIdx.x;
  if (t < nbk) tails[t] = 0;
}

// ---------- CSR build phase A ----------
__global__ __launch_bounds__(256) void bucket_k(const int* __restrict__ row,
                                                const int* __restrict__ col,
                                                int* __restrict__ tails,
                                                unsigned int* __restrict__ buckets,
                                                int E, int nbk) {
  __shared__ int bcnt[NBK_MAX], bex[NBK_MAX], bnext[NBK_MAX], gbase[NBK_MAX];
  __shared__ int ssc[256];
  int t = threadIdx.x;
  int ts = blockIdx.x * TILE_A;
  int tn = E - ts;
  if (tn > TILE_A) tn = TILE_A;
  bcnt[t] = 0;
  bcnt[t + 256] = 0;
  __syncthreads();
  for (int i = t; i < tn; i += 256) atomicAdd(&bcnt[row[ts + i] >> 8], 1);
  __syncthreads();
  int a0 = bcnt[2 * t], a1 = bcnt[2 * t + 1];
  ssc[t] = a0 + a1;
  __syncthreads();
  #pragma unroll
  for (int off = 1; off < 256; off <<= 1) {
    int x = (t >= off) ? ssc[t - off] : 0;
    __syncthreads();
    ssc[t] += x;
    __syncthreads();
  }
  int ex = ssc[t] - (a0 + a1);
  bex[2 * t] = ex;
  bex[2 * t + 1] = ex + a0;
  bnext[2 * t] = ex;
  bnext[2 * t + 1] = ex + a0;
  if (t < nbk && bcnt[t] > 0) gbase[t] = atomicAdd(&tails[t], bcnt[t]);
  int t2 = t + 256;
  if (t2 < nbk && bcnt[t2] > 0) gbase[t2] = atomicAdd(&tails[t2], bcnt[t2]);
  __syncthreads();
  for (int i = t; i < tn; i += 256) {
    int r = row[ts + i], c = col[ts + i];
    int b = r >> 8;
    int k = atomicAdd(&bnext[b], 1) - bex[b];
    int pos = gbase[b] + k;
    if (pos < BCAP)
      buckets[(size_t)b * BCAP + pos] = ((unsigned)(r & 255) << 24) | (unsigned)c;
  }
}

__global__ __launch_bounds__(512) void bkscan_k(const int* __restrict__ tails,
                                                int* __restrict__ bkbase,
                                                int* __restrict__ rp,
                                                int nbk, int N, int E) {
  __shared__ int s[512];
  int t = threadIdx.x;
  int v = (t < nbk) ? tails[t] : 0;
  s[t] = v;
  __syncthreads();
  #pragma unroll
  for (int off = 1; off < 512; off <<= 1) {
    int x = (t >= off) ? s[t - off] : 0;
    __syncthreads();
    s[t] += x;
    __syncthreads();
  }
  if (t < nbk) bkbase[t] = s[t] - v;
  if (t == 0) rp[N] = E;
}

// ---------- CSR build phase B + folded copyx ----------
// Per 256-row bucket: per-row counts, scan, scatter to final CSR, write rp and
// dinv; then stream out[:,0:64]=x (f32) and xg = bf16(dinv*x) for these rows.
__global__ __launch_bounds__(256) void csr_k(const int* __restrict__ tails,
                                             const int* __restrict__ bkbase,
                                             const unsigned int* __restrict__ buckets,
                                             int* __restrict__ rp,
                                             float* __restrict__ dinv,
                                             int* __restrict__ packed,
                                             const float* __restrict__ x,
                                             float* __restrict__ out,
                                             ushort_t* __restrict__ xg,
                                             int N, int ostride4) {
  __shared__ int cnt[256], sc[256], cnt2[256];
  __shared__ float sdinv[256];
  int b = blockIdx.x, t = threadIdx.x;
  int row0 = b << 8;
  int nrows = N - row0;
  if (nrows > 256) nrows = 256;
  int cb = tails[b];
  if (cb > BCAP) cb = BCAP;
  int base = bkbase[b];
  const unsigned int* ent = buckets + (size_t)b * BCAP;
  cnt[t] = 0;
  __syncthreads();
  for (int i = t; i < cb; i += 256) atomicAdd(&cnt[ent[i] >> 24], 1);
  __syncthreads();
  int v = cnt[t];
  sc[t] = v;
  __syncthreads();
  #pragma unroll
  for (int off = 1; off < 256; off <<= 1) {
    int x2 = (t >= off) ? sc[t - off] : 0;
    __syncthreads();
    sc[t] += x2;
    __syncthreads();
  }
  int ex = sc[t] - v;
  float dvv = (v > 0) ? rsqrtf((float)v) : 0.f;
  sdinv[t] = dvv;
  if (t < nrows) {
    rp[row0 + t] = base + ex;
    dinv[row0 + t] = dvv;
  }
  cnt[t] = ex;
  cnt2[t] = 0;
  __syncthreads();
  for (int i = t; i < cb; i += 256) {
    unsigned e = ent[i];
    int rl = e >> 24;
    int slot = atomicAdd(&cnt2[rl], 1);
    packed[base + cnt[rl] + slot] = (int)(e & 0xFFFFFFu);
  }
  // folded copyx for rows row0 .. row0+nrows-1
  int base4 = row0 << 4;
  int tot4 = nrows << 4;
  for (int i = t; i < tot4; i += 256) {
    int rl = i >> 4, c4 = i & 15;
    float4 vx = ((const float4*)x)[base4 + i];
    ((float4*)out)[(size_t)(row0 + rl) * ostride4 + c4] = vx;
    float dv = sdinv[rl];
    unsigned q0 = f2bf(vx.x * dv) | (f2bf(vx.y * dv) << 16);
    unsigned q1 = f2bf(vx.z * dv) | (f2bf(vx.w * dv) << 16);
    ((uint2*)xg)[base4 + i] = make_uint2(q0, q1);
  }
}

// ---------- pack W (f32 [k][64][64]) into mfma fragment order, bf16 ----------
__global__ __launch_bounds__(256) void packw_k(const float* __restrict__ Wg,
                                               const float* __restrict__ Wi,
                                               ushort_t* __restrict__ Wfrag,
                                               int total) {
  int tid = blockIdx.x * 256 + threadIdx.x;
  if (tid >= total) return;
  int lane = tid & 63;
  int kh = (tid >> 6) & 1;
  int nt = (tid >> 7) & 3;
  int gm = (tid >> 9) & 1;
  int ly = tid >> 10;
  const float* W = (gm ? Wi : Wg) + (size_t)ly * 4096;
  int kb = (kh << 5) + ((lane >> 4) << 3);
  int n = (nt << 4) + (lane & 15);
  unsigned u[4];
  #pragma unroll
  for (int j = 0; j < 4; ++j) {
    unsigned lo = f2bf(W[(kb + 2 * j) * 64 + n]);
    unsigned hi = f2bf(W[(kb + 2 * j + 1) * 64 + n]);
    u[j] = lo | (hi << 16);
  }
  ((uint4*)Wfrag)[tid] = make_uint4(u[0], u[1], u[2], u[3]);
}

// ---------- aggregation: TWO nodes per wave; 8 edges per load instruction ----
// ha[r] = dinv[r] * sum_{c in N(r)} g[c]   (g = dinv*h pre-folded, bf16)
__global__ __launch_bounds__(256) void agg_k(const int* __restrict__ rp,
                                             const int* __restrict__ packed,
                                             const float* __restrict__ dinv,
                                             const ushort_t* __restrict__ gin,
                                             ushort_t* __restrict__ ha, int N) {
  int wv = (((blockIdx.x << 2) + (threadIdx.x >> 6)) << 1);
  if (wv >= N) return;
  int lane = threadIdx.x & 63;
  int grp = lane >> 3;
  int l8 = lane & 7;
  bool have1 = (wv + 1) < N;
  int s0 = rfl(&rp[wv]);
  int e0 = rfl(&rp[wv + 1]);
  int s1 = have1 ? rfl(&rp[wv + 1]) : 0;
  int e1 = have1 ? rfl(&rp[wv + 2]) : 0;
  float dr0 = __int_as_float(__builtin_amdgcn_readfirstlane(__float_as_int(dinv[wv])));
  float dr1 = have1 ? __int_as_float(__builtin_amdgcn_readfirstlane(
                          __float_as_int(dinv[wv + 1])))
                    : 0.f;
  float a0[8], a1[8];
  #pragma unroll
  for (int i = 0; i < 8; ++i) { a0[i] = 0.f; a1[i] = 0.f; }
  int bidx0 = grp << 2;  // bpermute byte base for edge (j*8 + grp)
  int ch0 = s0, ch1 = s1;
  while (ch0 < e0 || ch1 < e1) {
    int m0 = e0 - ch0;
    if (m0 > 64) m0 = 64;
    int m1 = e1 - ch1;
    if (m1 > 64) m1 = 64;
    int cl0 = (m0 > 0 && lane < m0) ? packed[ch0 + lane] : 0;
    int cl1 = (m1 > 0 && lane < m1) ? packed[ch1 + lane] : 0;
    int mm = m0 > m1 ? m0 : m1;
    int nit = (mm + 7) >> 3;
    #pragma unroll 2
    for (int j = 0; j < nit; ++j) {
      int bi = bidx0 + (j << 5);
      int c0 = __builtin_amdgcn_ds_bpermute(bi, cl0);
      int c1 = __builtin_amdgcn_ds_bpermute(bi, cl1);
      int eidx = (j << 3) + grp;
      float msk0 = (eidx < m0) ? 1.f : 0.f;
      float msk1 = (eidx < m1) ? 1.f : 0.f;
      uint4 v0 = ((const uint4*)(gin + ((size_t)c0 << 6)))[l8];
      uint4 v1 = ((const uint4*)(gin + ((size_t)c1 << 6)))[l8];
      a0[0] = fmaf(msk0, bf2f(v0.x & 0xFFFFu), a0[0]);
      a0[1] = fmaf(msk0, bf2f(v0.x >> 16), a0[1]);
      a0[2] = fmaf(msk0, bf2f(v0.y & 0xFFFFu), a0[2]);
      a0[3] = fmaf(msk0, bf2f(v0.y >> 16), a0[3]);
      a0[4] = fmaf(msk0, bf2f(v0.z & 0xFFFFu), a0[4]);
      a0[5] = fmaf(msk0, bf2f(v0.z >> 16), a0[5]);
      a0[6] = fmaf(msk0, bf2f(v0.w & 0xFFFFu), a0[6]);
      a0[7] = fmaf(msk0, bf2f(v0.w >> 16), a0[7]);
      a1[0] = fmaf(msk1, bf2f(v1.x & 0xFFFFu), a1[0]);
      a1[1] = fmaf(msk1, bf2f(v1.x >> 16), a1[1]);
      a1[2] = fmaf(msk1, bf2f(v1.y & 0xFFFFu), a1[2]);
      a1[3] = fmaf(msk1, bf2f(v1.y >> 16), a1[3]);
      a1[4] = fmaf(msk1, bf2f(v1.z & 0xFFFFu), a1[4]);
      a1[5] = fmaf(msk1, bf2f(v1.z >> 16), a1[5]);
      a1[6] = fmaf(msk1, bf2f(v1.w & 0xFFFFu), a1[6]);
      a1[7] = fmaf(msk1, bf2f(v1.w >> 16), a1[7]);
    }
    ch0 += 64;
    ch1 += 64;
  }
  #pragma unroll
  for (int off = 8; off < 64; off <<= 1)
    #pragma unroll
    for (int i = 0; i < 8; ++i) {
      a0[i] += __shfl_xor(a0[i], off);
      a1[i] += __shfl_xor(a1[i], off);
    }
  if (grp == 0) {
    unsigned u0 = f2bf(a0[0] * dr0) | (f2bf(a0[1] * dr0) << 16);
    unsigned u1 = f2bf(a0[2] * dr0) | (f2bf(a0[3] * dr0) << 16);
    unsigned u2 = f2bf(a0[4] * dr0) | (f2bf(a0[5] * dr0) << 16);
    unsigned u3 = f2bf(a0[6] * dr0) | (f2bf(a0[7] * dr0) << 16);
    ((uint4*)(ha + ((size_t)wv << 6)))[l8] = make_uint4(u0, u1, u2, u3);
  } else if (grp == 1 && have1) {
    unsigned u0 = f2bf(a1[0] * dr1) | (f2bf(a1[1] * dr1) << 16);
    unsigned u1 = f2bf(a1[2] * dr1) | (f2bf(a1[3] * dr1) << 16);
    unsigned u2 = f2bf(a1[4] * dr1) | (f2bf(a1[5] * dr1) << 16);
    unsigned u3 = f2bf(a1[6] * dr1) | (f2bf(a1[7] * dr1) << 16);
    ((uint4*)(ha + ((size_t)(wv + 1) << 6)))[l8] = make_uint4(u0, u1, u2, u3);
  }
}

// ---------- fused dual-GEMM via MFMA, wave-per-16-rows ----------
// h is reconstructed as g * (1/dinv) per A-fragment row (deg-0 rows -> 0).
// Emits gout = bf16(dinv[r]*z) (next layer state) and outp = f32 l2norm(z).
__global__ __launch_bounds__(256) void gemmM_k(const ushort_t* __restrict__ ha,
                                               const ushort_t* __restrict__ gin,
                                               const ushort_t* __restrict__ Wfrag,
                                               const float* __restrict__ bg,
                                               const float* __restrict__ bi,
                                               const float* __restrict__ dinv,
                                               ushort_t* __restrict__ gout,
                                               float* __restrict__ outp,
                                               int N, int ntiles, int ostride) {
  int lane = threadIdx.x & 63;
  int gq = lane >> 4, ln15 = lane & 15;
  const short8* wf = (const short8*)Wfrag;
  short8 bG[8], bI[8];
  #pragma unroll
  for (int nt = 0; nt < 4; ++nt)
    #pragma unroll
    for (int kh = 0; kh < 2; ++kh) {
      bG[nt * 2 + kh] = wf[nt * 128 + kh * 64 + lane];
      bI[nt * 2 + kh] = wf[512 + nt * 128 + kh * 64 + lane];
    }
  float bgv[4], biv[4];
  #pragma unroll
  for (int nt = 0; nt < 4; ++nt) {
    bgv[nt] = bg[nt * 16 + ln15];
    biv[nt] = bi[nt * 16 + ln15];
  }
  int wid = (blockIdx.x << 2) + (threadIdx.x >> 6);
  int nw = gridDim.x << 2;
  for (int tile = wid; tile < ntiles; tile += nw) {
    int node0 = tile << 4;
    int r15 = node0 + ln15;
    float dnv = dinv[r15];
    float rdv = (dnv > 0.f) ? 1.f / dnv : 0.f;
    const short8* pa = (const short8*)(ha + (size_t)r15 * 64 + gq * 8);
    const short8* ph = (const short8*)(gin + (size_t)r15 * 64 + gq * 8);
    f32x4 acc1[4], acc2[4];
    #pragma unroll
    for (int nt = 0; nt < 4; ++nt) {
      acc1[nt] = (f32x4){bgv[nt], bgv[nt], bgv[nt], bgv[nt]};
      acc2[nt] = (f32x4){biv[nt], biv[nt], biv[nt], biv[nt]};
    }
    #pragma unroll
    for (int kh = 0; kh < 2; ++kh) {
      short8 af = pa[kh * 4];
      short8 gf = ph[kh * 4];
      short8 vmf;
      #pragma unroll
      for (int e2 = 0; e2 < 8; ++e2) {
        float fa = bf2f((ushort_t)af[e2]);
        float fh = bf2f((ushort_t)gf[e2]) * rdv;  // h = g / dinv
        vmf[e2] = (short)f2bf(fa * fh);
      }
      #pragma unroll
      for (int nt = 0; nt < 4; ++nt) {
        acc1[nt] = __builtin_amdgcn_mfma_f32_16x16x32_bf16(af, bG[nt * 2 + kh],
                                                           acc1[nt], 0, 0, 0);
        acc2[nt] = __builtin_amdgcn_mfma_f32_16x16x32_bf16(vmf, bI[nt * 2 + kh],
                                                           acc2[nt], 0, 0, 0);
      }
    }
    float z[4][4];
    float ssr[4] = {0.f, 0.f, 0.f, 0.f};
    #pragma unroll
    for (int nt = 0; nt < 4; ++nt)
      #pragma unroll
      for (int reg = 0; reg < 4; ++reg) {
        float zz = lrelu(acc1[nt][reg]) + lrelu(acc2[nt][reg]);
        z[nt][reg] = zz;
        ssr[reg] = fmaf(zz, zz, ssr[reg]);
      }
    #pragma unroll
    for (int off = 1; off < 16; off <<= 1)
      #pragma unroll
      for (int reg = 0; reg < 4; ++reg) ssr[reg] += __shfl_xor(ssr[reg], off);
    float inv[4];
    #pragma unroll
    for (int reg = 0; reg < 4; ++reg)
      inv[reg] = rsqrtf(fmaxf(ssr[reg], 1e-12f));
    #pragma unroll
    for (int reg = 0; reg < 4; ++reg) {
      int r = node0 + 4 * gq + reg;
      if (r < N) {
        float dv = dinv[r];
        #pragma unroll
        for (int nt = 0; nt < 4; ++nt) {
          outp[(size_t)r * ostride + nt * 16 + ln15] = z[nt][reg] * inv[reg];
          gout[(size_t)r * 64 + nt * 16 + ln15] =
              (ushort_t)f2bf(z[nt][reg] * dv);
        }
      }
    }
  }
}

extern "C" void kernel_launch(void* const* d_in, const int* in_sizes, int n_in,
                              void* d_out, int out_size, void* d_ws, size_t ws_size,
                              hipStream_t stream) {
  const float* x  = (const float*)d_in[0];
  const int*   ei = (const int*)d_in[1];
  const float* Wg = (const float*)d_in[2];
  const float* bg = (const float*)d_in[3];
  const float* Wi = (const float*)d_in[4];
  const float* bi = (const float*)d_in[5];
  float* out = (float*)d_out;

  const int d = 64;
  const int N = in_sizes[0] / d;
  const int E = in_sizes[1] / 2;
  const int K = in_sizes[2] / (d * d);
  const int* row = ei;
  const int* col = ei + E;
  const int nbk = (N + 255) / 256;
  const int N16 = (N + 15) & ~15;
  const int ntiles = N16 / 16;
  const int ostride = (K + 1) * d;

  char* ws = (char*)d_ws;
  size_t off = 0;
  auto alloc = [&](size_t bytes) {
    char* p = ws + off;
    off = (off + bytes + 255) & ~(size_t)255;
    return p;
  };
  int*   tails  = (int*)alloc((size_t)NBK_MAX * 4);
  int*   bkbase = (int*)alloc((size_t)NBK_MAX * 4);
  int*   rp     = (int*)alloc((size_t)(N + 1) * 4);
  float* dinv   = (float*)alloc((size_t)N16 * 4);
  unsigned int* buckets = (unsigned int*)alloc((size_t)nbk * BCAP * 4);
  int*   packed = (int*)alloc((size_t)E * 4);
  ushort_t* ha  = (ushort_t*)alloc((size_t)N16 * d * 2);
  ushort_t* hg0 = (ushort_t*)alloc((size_t)N16 * d * 2);
  ushort_t* hg1 = (ushort_t*)alloc((size_t)N16 * d * 2);
  ushort_t* xg  = (ushort_t*)alloc((size_t)N16 * d * 2);
  ushort_t* Wfrag = (ushort_t*)alloc((size_t)K * 8192 * 2);
  (void)ws_size;

  zerotails_k<<<(nbk + 255) / 256, 256, 0, stream>>>(tails, nbk);
  int ntA = (E + TILE_A - 1) / TILE_A;
  bucket_k<<<ntA, 256, 0, stream>>>(row, col, tails, buckets, E, nbk);
  bkscan_k<<<1, 512, 0, stream>>>(tails, bkbase, rp, nbk, N, E);
  csr_k<<<nbk, 256, 0, stream>>>(tails, bkbase, buckets, rp, dinv, packed,
                                 x, out, xg, N, ostride / 4);
  int wtotal = K * 1024;
  packw_k<<<(wtotal + 255) / 256, 256, 0, stream>>>(Wg, Wi, Wfrag, wtotal);

  const ushort_t* gin = xg;
  ushort_t* gbufs[2] = {hg0, hg1};
  int aggblocks = (N + 7) / 8;          // 4 waves/block, 2 nodes/wave
  int gemmblocks = (ntiles + 3) / 4;    // 1 tile/wave
  for (int i = 0; i < K; ++i) {
    ushort_t* gout = gbufs[i & 1];
    agg_k<<<aggblocks, 256, 0, stream>>>(rp, packed, dinv, gin, ha, N);
    gemmM_k<<<gemmblocks, 256, 0, stream>>>(
        ha, gin, Wfrag + (size_t)i * 8192, bg + (size_t)i * d,
        bi + (size_t)i * d, dinv, gout, out + (size_t)(i + 1) * d,
        N, ntiles, ostride);
    gin = gout;
  }
}

// Round 12
// 223.650 us; speedup vs baseline: 1.0347x; 1.0347x over previous
//
#include <hip/hip_runtime.h>

// NGCF-style GNN: 3 layers of {sparse sym-normalized aggregation, two 64x64 GEMMs,
// leaky-relu, l2norm}. CSR built on-device per call via bucketed counting sort.
// h stored bf16; gather operand g[c] = dinv[c]*h[c] stored FP8 E4M3 (64B rows).
// Aggregation keeps R10's measured-best MLP shape: TWO nodes per wave, 8 lanes
// per row (uint2 = 8 fp8/lane), 8 edges per load, 4 gathers in flight (r9
// lesson: fp8 fails if it cuts loads-in-flight; r10 lesson: agg is fabric-
// request-bound). GEMMs via mfma_f32_16x16x32_bf16, W pre-packed. No
// hipMemsetAsync in graph; tails zeroed inside packw_k (launched first).
//
// Assumes N <= 131072 (512 buckets of 256 rows).

#define LEAKY 0.2f
#define NBK_MAX 512
#define TILE_A 4096
#define BCAP 5120

typedef unsigned short ushort_t;
typedef unsigned char uchar_t;
typedef short short8 __attribute__((ext_vector_type(8)));
typedef float f32x4 __attribute__((ext_vector_type(4)));
typedef float f32x2 __attribute__((ext_vector_type(2)));

__device__ __forceinline__ float lrelu(float z) { return z > 0.f ? z : LEAKY * z; }

__device__ __forceinline__ unsigned f2bf(float f) {  // RNE
  unsigned u = __float_as_uint(f);
  return (u + 0x7FFFu + ((u >> 16) & 1u)) >> 16;
}

__device__ __forceinline__ float bf2f(unsigned u) {
  return __uint_as_float(u << 16);
}

__device__ __forceinline__ unsigned f2fp8(float f) {  // 1 byte e4m3 (HW RNE)
  return (unsigned)__builtin_amdgcn_cvt_pk_fp8_f32(f, f, 0, false) & 0xFFu;
}

__device__ __forceinline__ int rfl(const int* p) {
  return __builtin_amdgcn_readfirstlane(*p);
}

// ---------- CSR build phase A ----------
__global__ __launch_bounds__(256) void bucket_k(const int* __restrict__ row,
                                                const int* __restrict__ col,
                                                int* __restrict__ tails,
                                                unsigned int* __restrict__ buckets,
                                                int E, int nbk) {
  __shared__ int bcnt[NBK_MAX], bex[NBK_MAX], bnext[NBK_MAX], gbase[NBK_MAX];
  __shared__ int ssc[256];
  int t = threadIdx.x;
  int ts = blockIdx.x * TILE_A;
  int tn = E - ts;
  if (tn > TILE_A) tn = TILE_A;
  bcnt[t] = 0;
  bcnt[t + 256] = 0;
  __syncthreads();
  for (int i = t; i < tn; i += 256) atomicAdd(&bcnt[row[ts + i] >> 8], 1);
  __syncthreads();
  int a0 = bcnt[2 * t], a1 = bcnt[2 * t + 1];
  ssc[t] = a0 + a1;
  __syncthreads();
  #pragma unroll
  for (int off = 1; off < 256; off <<= 1) {
    int x = (t >= off) ? ssc[t - off] : 0;
    __syncthreads();
    ssc[t] += x;
    __syncthreads();
  }
  int ex = ssc[t] - (a0 + a1);
  bex[2 * t] = ex;
  bex[2 * t + 1] = ex + a0;
  bnext[2 * t] = ex;
  bnext[2 * t + 1] = ex + a0;
  if (t < nbk && bcnt[t] > 0) gbase[t] = atomicAdd(&tails[t], bcnt[t]);
  int t2 = t + 256;
  if (t2 < nbk && bcnt[t2] > 0) gbase[t2] = atomicAdd(&tails[t2], bcnt[t2]);
  __syncthreads();
  for (int i = t; i < tn; i += 256) {
    int r = row[ts + i], c = col[ts + i];
    int b = r >> 8;
    int k = atomicAdd(&bnext[b], 1) - bex[b];
    int pos = gbase[b] + k;
    if (pos < BCAP)
      buckets[(size_t)b * BCAP + pos] = ((unsigned)(r & 255) << 24) | (unsigned)c;
  }
}

__global__ __launch_bounds__(512) void bkscan_k(const int* __restrict__ tails,
                                                int* __restrict__ bkbase,
                                                int* __restrict__ rp,
                                                int nbk, int N, int E) {
  __shared__ int s[512];
  int t = threadIdx.x;
  int v = (t < nbk) ? tails[t] : 0;
  s[t] = v;
  __syncthreads();
  #pragma unroll
  for (int off = 1; off < 512; off <<= 1) {
    int x = (t >= off) ? s[t - off] : 0;
    __syncthreads();
    s[t] += x;
    __syncthreads();
  }
  if (t < nbk) bkbase[t] = s[t] - v;
  if (t == 0) rp[N] = E;
}

__global__ __launch_bounds__(256) void csr_k(const int* __restrict__ tails,
                                             const int* __restrict__ bkbase,
                                             const unsigned int* __restrict__ buckets,
                                             int* __restrict__ rp,
                                             float* __restrict__ dinv,
                                             int* __restrict__ packed, int N) {
  __shared__ int cnt[256], sc[256], cnt2[256];
  int b = blockIdx.x, t = threadIdx.x;
  int row0 = b << 8;
  int nrows = N - row0;
  if (nrows > 256) nrows = 256;
  int cb = tails[b];
  if (cb > BCAP) cb = BCAP;
  int base = bkbase[b];
  const unsigned int* ent = buckets + (size_t)b * BCAP;
  cnt[t] = 0;
  __syncthreads();
  for (int i = t; i < cb; i += 256) atomicAdd(&cnt[ent[i] >> 24], 1);
  __syncthreads();
  int v = cnt[t];
  sc[t] = v;
  __syncthreads();
  #pragma unroll
  for (int off = 1; off < 256; off <<= 1) {
    int x = (t >= off) ? sc[t - off] : 0;
    __syncthreads();
    sc[t] += x;
    __syncthreads();
  }
  int ex = sc[t] - v;
  if (t < nrows) {
    rp[row0 + t] = base + ex;
    dinv[row0 + t] = (v > 0) ? rsqrtf((float)v) : 0.f;
  }
  cnt[t] = ex;
  cnt2[t] = 0;
  __syncthreads();
  for (int i = t; i < cb; i += 256) {
    unsigned e = ent[i];
    int rl = e >> 24;
    int slot = atomicAdd(&cnt2[rl], 1);
    packed[base + cnt[rl] + slot] = (int)(e & 0xFFFFFFu);
  }
}

// ---------- out[:, 0:64] = x (f32); xb = bf16(x); xg = fp8(dinv*x) ----------
__global__ __launch_bounds__(256) void copyx_k(const float* __restrict__ x,
                                               const float* __restrict__ dinv,
                                               float* __restrict__ out,
                                               ushort_t* __restrict__ xb,
                                               uchar_t* __restrict__ xg,
                                               int N, int ostride4) {
  int total = N * 16;
  int stride = gridDim.x * blockDim.x;
  for (int i = blockIdx.x * blockDim.x + threadIdx.x; i < total; i += stride) {
    int n = i >> 4, c4 = i & 15;
    float4 v = ((const float4*)x)[i];
    ((float4*)out)[(size_t)n * ostride4 + c4] = v;
    unsigned p0 = f2bf(v.x) | (f2bf(v.y) << 16);
    unsigned p1 = f2bf(v.z) | (f2bf(v.w) << 16);
    ((uint2*)xb)[i] = make_uint2(p0, p1);
    float dv = dinv[n];
    unsigned pkA =
        (unsigned)__builtin_amdgcn_cvt_pk_fp8_f32(v.x * dv, v.y * dv, 0, false);
    unsigned pkB =
        (unsigned)__builtin_amdgcn_cvt_pk_fp8_f32(v.z * dv, v.w * dv, 0, false);
    ((unsigned*)xg)[i] = (pkA & 0xFFFFu) | ((pkB & 0xFFFFu) << 16);
  }
}

// ---------- pack W into mfma fragment order (bf16); also zero tails ----------
__global__ __launch_bounds__(256) void packw_k(const float* __restrict__ Wg,
                                               const float* __restrict__ Wi,
                                               ushort_t* __restrict__ Wfrag,
                                               int total,
                                               int* __restrict__ tails, int nbk) {
  int tid = blockIdx.x * 256 + threadIdx.x;
  if (tid < nbk) tails[tid] = 0;
  if (tid >= total) return;
  int lane = tid & 63;
  int kh = (tid >> 6) & 1;
  int nt = (tid >> 7) & 3;
  int gm = (tid >> 9) & 1;
  int ly = tid >> 10;
  const float* W = (gm ? Wi : Wg) + (size_t)ly * 4096;
  int kb = (kh << 5) + ((lane >> 4) << 3);
  int n = (nt << 4) + (lane & 15);
  unsigned u[4];
  #pragma unroll
  for (int j = 0; j < 4; ++j) {
    unsigned lo = f2bf(W[(kb + 2 * j) * 64 + n]);
    unsigned hi = f2bf(W[(kb + 2 * j + 1) * 64 + n]);
    u[j] = lo | (hi << 16);
  }
  ((uint4*)Wfrag)[tid] = make_uint4(u[0], u[1], u[2], u[3]);
}

// ---------- aggregation: TWO nodes per wave; 8 edges per load instruction ----
// ha[r] = dinv[r] * sum_{c in N(r)} g[c]   (g fp8 e4m3, 64B rows)
// lane = (grp 0..7) x (l8 0..7); lane loads uint2 = 8 fp8 of row col[j*8+grp].
// Node A and node B chains interleaved -> 4 independent gathers in flight.
__global__ __launch_bounds__(256) void agg_k(const int* __restrict__ rp,
                                             const int* __restrict__ packed,
                                             const float* __restrict__ dinv,
                                             const uchar_t* __restrict__ gin,
                                             ushort_t* __restrict__ ha, int N) {
  int wv = (((blockIdx.x << 2) + (threadIdx.x >> 6)) << 1);
  if (wv >= N) return;
  int lane = threadIdx.x & 63;
  int grp = lane >> 3;
  int l8 = lane & 7;
  bool have1 = (wv + 1) < N;
  int s0 = rfl(&rp[wv]);
  int e0 = rfl(&rp[wv + 1]);
  int s1 = have1 ? rfl(&rp[wv + 1]) : 0;
  int e1 = have1 ? rfl(&rp[wv + 2]) : 0;
  float dr0 = __int_as_float(__builtin_amdgcn_readfirstlane(__float_as_int(dinv[wv])));
  float dr1 = have1 ? __int_as_float(__builtin_amdgcn_readfirstlane(
                          __float_as_int(dinv[wv + 1])))
                    : 0.f;
  float a0[8], a1[8];
  #pragma unroll
  for (int i = 0; i < 8; ++i) { a0[i] = 0.f; a1[i] = 0.f; }
  int bidx0 = grp << 2;  // bpermute byte base for edge (j*8 + grp)
  int ch0 = s0, ch1 = s1;
  while (ch0 < e0 || ch1 < e1) {
    int m0 = e0 - ch0;
    if (m0 > 64) m0 = 64;
    int m1 = e1 - ch1;
    if (m1 > 64) m1 = 64;
    int cl0 = (m0 > 0 && lane < m0) ? packed[ch0 + lane] : 0;
    int cl1 = (m1 > 0 && lane < m1) ? packed[ch1 + lane] : 0;
    int mm = m0 > m1 ? m0 : m1;
    int nit = (mm + 7) >> 3;
    #pragma unroll 2
    for (int j = 0; j < nit; ++j) {
      int bi = bidx0 + (j << 5);
      int c0 = __builtin_amdgcn_ds_bpermute(bi, cl0);
      int c1 = __builtin_amdgcn_ds_bpermute(bi, cl1);
      int eidx = (j << 3) + grp;
      float msk0 = (eidx < m0) ? 1.f : 0.f;
      float msk1 = (eidx < m1) ? 1.f : 0.f;
      uint2 v0 = ((const uint2*)(gin + ((size_t)c0 << 6)))[l8];
      uint2 v1 = ((const uint2*)(gin + ((size_t)c1 << 6)))[l8];
      f32x2 d;
      d = __builtin_amdgcn_cvt_pk_f32_fp8((int)v0.x, false);
      a0[0] = fmaf(msk0, d[0], a0[0]);  a0[1] = fmaf(msk0, d[1], a0[1]);
      d = __builtin_amdgcn_cvt_pk_f32_fp8((int)v0.x, true);
      a0[2] = fmaf(msk0, d[0], a0[2]);  a0[3] = fmaf(msk0, d[1], a0[3]);
      d = __builtin_amdgcn_cvt_pk_f32_fp8((int)v0.y, false);
      a0[4] = fmaf(msk0, d[0], a0[4]);  a0[5] = fmaf(msk0, d[1], a0[5]);
      d = __builtin_amdgcn_cvt_pk_f32_fp8((int)v0.y, true);
      a0[6] = fmaf(msk0, d[0], a0[6]);  a0[7] = fmaf(msk0, d[1], a0[7]);
      d = __builtin_amdgcn_cvt_pk_f32_fp8((int)v1.x, false);
      a1[0] = fmaf(msk1, d[0], a1[0]);  a1[1] = fmaf(msk1, d[1], a1[1]);
      d = __builtin_amdgcn_cvt_pk_f32_fp8((int)v1.x, true);
      a1[2] = fmaf(msk1, d[0], a1[2]);  a1[3] = fmaf(msk1, d[1], a1[3]);
      d = __builtin_amdgcn_cvt_pk_f32_fp8((int)v1.y, false);
      a1[4] = fmaf(msk1, d[0], a1[4]);  a1[5] = fmaf(msk1, d[1], a1[5]);
      d = __builtin_amdgcn_cvt_pk_f32_fp8((int)v1.y, true);
      a1[6] = fmaf(msk1, d[0], a1[6]);  a1[7] = fmaf(msk1, d[1], a1[7]);
    }
    ch0 += 64;
    ch1 += 64;
  }
  #pragma unroll
  for (int off = 8; off < 64; off <<= 1)
    #pragma unroll
    for (int i = 0; i < 8; ++i) {
      a0[i] += __shfl_xor(a0[i], off);
      a1[i] += __shfl_xor(a1[i], off);
    }
  if (grp == 0) {
    unsigned u0 = f2bf(a0[0] * dr0) | (f2bf(a0[1] * dr0) << 16);
    unsigned u1 = f2bf(a0[2] * dr0) | (f2bf(a0[3] * dr0) << 16);
    unsigned u2 = f2bf(a0[4] * dr0) | (f2bf(a0[5] * dr0) << 16);
    unsigned u3 = f2bf(a0[6] * dr0) | (f2bf(a0[7] * dr0) << 16);
    ((uint4*)(ha + ((size_t)wv << 6)))[l8] = make_uint4(u0, u1, u2, u3);
  } else if (grp == 1 && have1) {
    unsigned u0 = f2bf(a1[0] * dr1) | (f2bf(a1[1] * dr1) << 16);
    unsigned u1 = f2bf(a1[2] * dr1) | (f2bf(a1[3] * dr1) << 16);
    unsigned u2 = f2bf(a1[4] * dr1) | (f2bf(a1[5] * dr1) << 16);
    unsigned u3 = f2bf(a1[6] * dr1) | (f2bf(a1[7] * dr1) << 16);
    ((uint4*)(ha + ((size_t)(wv + 1) << 6)))[l8] = make_uint4(u0, u1, u2, u3);
  }
}

// ---------- fused dual-GEMM via MFMA, wave-per-16-rows grid-stride ----------
// Emits hout = bf16(z) and (if writeg) gout = fp8(dinv[r]*z) for next layer.
__global__ __launch_bounds__(256) void gemmM_k(const ushort_t* __restrict__ ha,
                                               const ushort_t* __restrict__ hin,
                                               const ushort_t* __restrict__ Wfrag,
                                               const float* __restrict__ bg,
                                               const float* __restrict__ bi,
                                               const float* __restrict__ dinv,
                                               ushort_t* __restrict__ hout,
                                               uchar_t* __restrict__ gout,
                                               float* __restrict__ outp,
                                               int N, int ntiles, int ostride,
                                               int writeg) {
  int lane = threadIdx.x & 63;
  int gq = lane >> 4, ln15 = lane & 15;
  const short8* wf = (const short8*)Wfrag;
  short8 bG[8], bI[8];
  #pragma unroll
  for (int nt = 0; nt < 4; ++nt)
    #pragma unroll
    for (int kh = 0; kh < 2; ++kh) {
      bG[nt * 2 + kh] = wf[nt * 128 + kh * 64 + lane];
      bI[nt * 2 + kh] = wf[512 + nt * 128 + kh * 64 + lane];
    }
  float bgv[4], biv[4];
  #pragma unroll
  for (int nt = 0; nt < 4; ++nt) {
    bgv[nt] = bg[nt * 16 + ln15];
    biv[nt] = bi[nt * 16 + ln15];
  }
  int wid = (blockIdx.x << 2) + (threadIdx.x >> 6);
  int nw = gridDim.x << 2;
  for (int tile = wid; tile < ntiles; tile += nw) {
    int node0 = tile << 4;
    const short8* pa =
        (const short8*)(ha + (size_t)(node0 + ln15) * 64 + gq * 8);
    const short8* ph =
        (const short8*)(hin + (size_t)(node0 + ln15) * 64 + gq * 8);
    f32x4 acc1[4], acc2[4];
    #pragma unroll
    for (int nt = 0; nt < 4; ++nt) {
      acc1[nt] = (f32x4){bgv[nt], bgv[nt], bgv[nt], bgv[nt]};
      acc2[nt] = (f32x4){biv[nt], biv[nt], biv[nt], biv[nt]};
    }
    #pragma unroll
    for (int kh = 0; kh < 2; ++kh) {
      short8 af = pa[kh * 4];
      short8 hf = ph[kh * 4];
      short8 vmf;
      #pragma unroll
      for (int e2 = 0; e2 < 8; ++e2) {
        float fa = bf2f((ushort_t)af[e2]);
        float fh = bf2f((ushort_t)hf[e2]);
        vmf[e2] = (short)f2bf(fa * fh);
      }
      #pragma unroll
      for (int nt = 0; nt < 4; ++nt) {
        acc1[nt] = __builtin_amdgcn_mfma_f32_16x16x32_bf16(af, bG[nt * 2 + kh],
                                                           acc1[nt], 0, 0, 0);
        acc2[nt] = __builtin_amdgcn_mfma_f32_16x16x32_bf16(vmf, bI[nt * 2 + kh],
                                                           acc2[nt], 0, 0, 0);
      }
    }
    float z[4][4];
    float ssr[4] = {0.f, 0.f, 0.f, 0.f};
    #pragma unroll
    for (int nt = 0; nt < 4; ++nt)
      #pragma unroll
      for (int reg = 0; reg < 4; ++reg) {
        float zz = lrelu(acc1[nt][reg]) + lrelu(acc2[nt][reg]);
        z[nt][reg] = zz;
        ssr[reg] = fmaf(zz, zz, ssr[reg]);
      }
    #pragma unroll
    for (int off = 1; off < 16; off <<= 1)
      #pragma unroll
      for (int reg = 0; reg < 4; ++reg) ssr[reg] += __shfl_xor(ssr[reg], off);
    float inv[4];
    #pragma unroll
    for (int reg = 0; reg < 4; ++reg)
      inv[reg] = rsqrtf(fmaxf(ssr[reg], 1e-12f));
    #pragma unroll
    for (int reg = 0; reg < 4; ++reg) {
      int r = node0 + 4 * gq + reg;
      if (r < N) {
        float dv = dinv[r];
        #pragma unroll
        for (int nt = 0; nt < 4; ++nt) {
          outp[(size_t)r * ostride + nt * 16 + ln15] = z[nt][reg] * inv[reg];
          hout[(size_t)r * 64 + nt * 16 + ln15] = (ushort_t)f2bf(z[nt][reg]);
          if (writeg)
            gout[(size_t)r * 64 + nt * 16 + ln15] =
                (uchar_t)f2fp8(z[nt][reg] * dv);
        }
      }
    }
  }
}

extern "C" void kernel_launch(void* const* d_in, const int* in_sizes, int n_in,
                              void* d_out, int out_size, void* d_ws, size_t ws_size,
                              hipStream_t stream) {
  const float* x  = (const float*)d_in[0];
  const int*   ei = (const int*)d_in[1];
  const float* Wg = (const float*)d_in[2];
  const float* bg = (const float*)d_in[3];
  const float* Wi = (const float*)d_in[4];
  const float* bi = (const float*)d_in[5];
  float* out = (float*)d_out;

  const int d = 64;
  const int N = in_sizes[0] / d;
  const int E = in_sizes[1] / 2;
  const int K = in_sizes[2] / (d * d);
  const int* row = ei;
  const int* col = ei + E;
  const int nbk = (N + 255) / 256;
  const int N16 = (N + 15) & ~15;
  const int ntiles = N16 / 16;
  const int ostride = (K + 1) * d;

  char* ws = (char*)d_ws;
  size_t off = 0;
  auto alloc = [&](size_t bytes) {
    char* p = ws + off;
    off = (off + bytes + 255) & ~(size_t)255;
    return p;
  };
  int*   tails  = (int*)alloc((size_t)NBK_MAX * 4);
  int*   bkbase = (int*)alloc((size_t)NBK_MAX * 4);
  int*   rp     = (int*)alloc((size_t)(N + 1) * 4);
  float* dinv   = (float*)alloc((size_t)N16 * 4);
  unsigned int* buckets = (unsigned int*)alloc((size_t)nbk * BCAP * 4);
  int*   packed = (int*)alloc((size_t)E * 4);
  ushort_t* ha  = (ushort_t*)alloc((size_t)N16 * d * 2);
  ushort_t* hb0 = (ushort_t*)alloc((size_t)N16 * d * 2);
  ushort_t* hb1 = (ushort_t*)alloc((size_t)N16 * d * 2);
  ushort_t* xb  = (ushort_t*)alloc((size_t)N16 * d * 2);
  uchar_t* hg0  = (uchar_t*)alloc((size_t)N16 * d);
  uchar_t* hg1  = (uchar_t*)alloc((size_t)N16 * d);
  uchar_t* xg   = (uchar_t*)alloc((size_t)N16 * d);
  ushort_t* Wfrag = (ushort_t*)alloc((size_t)K * 8192 * 2);
  (void)ws_size;

  int wtotal = K * 1024;
  packw_k<<<(wtotal + 255) / 256, 256, 0, stream>>>(Wg, Wi, Wfrag, wtotal,
                                                    tails, nbk);
  int ntA = (E + TILE_A - 1) / TILE_A;
  bucket_k<<<ntA, 256, 0, stream>>>(row, col, tails, buckets, E, nbk);
  bkscan_k<<<1, 512, 0, stream>>>(tails, bkbase, rp, nbk, N, E);
  csr_k<<<nbk, 256, 0, stream>>>(tails, bkbase, buckets, rp, dinv, packed, N);
  copyx_k<<<2048, 256, 0, stream>>>(x, dinv, out, xb, xg, N, ostride / 4);

  const ushort_t* hin = xb;
  const uchar_t* gin = xg;
  ushort_t* hbufs[2] = {hb0, hb1};
  uchar_t* gbufs[2] = {hg0, hg1};
  int aggblocks = (N + 7) / 8;  // 4 waves/block, 2 nodes/wave
  for (int i = 0; i < K; ++i) {
    ushort_t* hout = hbufs[i & 1];
    uchar_t* gout = gbufs[i & 1];
    agg_k<<<aggblocks, 256, 0, stream>>>(rp, packed, dinv, gin, ha, N);
    gemmM_k<<<1024, 256, 0, stream>>>(
        ha, hin, Wfrag + (size_t)i * 8192, bg + (size_t)i * d,
        bi + (size_t)i * d, dinv, hout, gout, out + (size_t)(i + 1) * d,
        N, ntiles, ostride, (i + 1 < K) ? 1 : 0);
    hin = hout;
    gin = gout;
  }
}